// Round 16
// baseline (469.360 us; speedup 1.0000x reference)
//
#include <hip/hip_runtime.h>
#include <cmath>

#define LOG2E 1.4426950408889634f
#define LN2   0.6931471805599453f
#define C8    0.00390625f   // 2^-8

constexpr int Bb = 8;
constexpr int Ll = 4096;
constexpr int Mrows = Bb * Ll;      // 32768
constexpr int NC = 128;             // chunks per sequence
constexpr int CL = Ll / NC;         // 32 steps per chunk

typedef unsigned short u16;
typedef short s16x8 __attribute__((ext_vector_type(8)));
typedef float f32x4 __attribute__((ext_vector_type(4)));

__device__ __forceinline__ float hexp2(float x) { return __builtin_amdgcn_exp2f(x); }
__device__ __forceinline__ float hlog2(float x) { return __builtin_amdgcn_logf(x); }
__device__ __forceinline__ float hrcp(float x)  { return __builtin_amdgcn_rcpf(x); }

__device__ __forceinline__ float softplus_f(float x) {
  const float t = hexp2(-fabsf(x) * LOG2E);
  return fmaxf(x, 0.f) + LN2 * hlog2(1.f + t);
}
__device__ __forceinline__ float sigmoid_f(float x) {
  return hrcp(1.f + hexp2(-x * LOG2E));
}
// causal depthwise conv (k=4) + bias + silu — exact op order (bit-identical u)
__device__ __forceinline__ float conv_u(float x3, float x2, float x1, float x0,
                                        float4 w, float bias) {
  float acc = 0.f;
  acc = fmaf(x3, w.x, acc);
  acc = fmaf(x2, w.y, acc);
  acc = fmaf(x1, w.z, acc);
  acc = fmaf(x0, w.w, acc);
  acc += bias;
  return acc * sigmoid_f(acc);
}

__device__ __forceinline__ f32x4 mfma_bf(s16x8 a, s16x8 b, f32x4 c) {
  return __builtin_amdgcn_mfma_f32_16x16x32_bf16(a, b, c, 0, 0, 0);
}

// bf16 RNE; 3-plane split is lossless for fp32 (24-bit mantissa = 3x8)
__device__ __forceinline__ u16 bf16rne(float v) {
  unsigned u = __float_as_uint(v);
  u += 0x7FFFu + ((u >> 16) & 1u);
  return (u16)(u >> 16);
}
__device__ __forceinline__ float bf2f(u16 h) {
  return __uint_as_float(((unsigned)h) << 16);
}
__device__ __forceinline__ void split3(float v, u16& h, u16& m, u16& l) {
  h = bf16rne(v);
  const float r1 = (v - bf2f(h)) * 256.f;
  m = bf16rne(r1);
  const float r2 = (r1 - bf2f(m)) * 256.f;
  l = bf16rne(r2);
}

// ---------------------------------------------------------------------------
__global__ __launch_bounds__(256) void k_split3(const float* __restrict__ src,
                                                u16* __restrict__ h,
                                                u16* __restrict__ m,
                                                u16* __restrict__ l, int n) {
  const int i = blockIdx.x * 256 + threadIdx.x;
  if (i < n) {
    u16 a, b, c;
    split3(src[i], a, b, c);
    h[i] = a; m[i] = b; l[i] = c;
  }
}

// ---------------------------------------------------------------------------
// Token embedding -> writes xb as 3 bf16 planes (producer-side split)
// ---------------------------------------------------------------------------
__global__ __launch_bounds__(128) void k_embed(const float* __restrict__ t,
                                               const float* __restrict__ w,
                                               u16* __restrict__ xh,
                                               u16* __restrict__ xm,
                                               u16* __restrict__ xl) {
  __shared__ float ws[128 * 27];
  const int d = threadIdx.x;
  for (int i = d; i < 128 * 27; i += 128) ws[i] = w[i];
  __syncthreads();
  const int bpb = Ll / 32;
  const int b = blockIdx.x / bpb;
  const int l0 = (blockIdx.x % bpb) * 32;
  const float* wd = &ws[d * 27];
  for (int l = l0; l < l0 + 32; ++l) {
    float acc = 0.f;
#pragma unroll
    for (int k = 0; k < 3; ++k) {
      int li = l + k - 1;
      if (li < 0) li += Ll;
      if (li >= Ll) li -= Ll;
      const float* tr = t + ((size_t)b * Ll + li) * 9;
#pragma unroll
      for (int c = 0; c < 9; ++c) acc = fmaf(tr[c], wd[c * 3 + k], acc);
    }
    const size_t idx = ((size_t)b * Ll + l) * 128 + d;
    u16 h, m, lo;
    split3(acc, h, m, lo);
    xh[idx] = h; xm[idx] = m; xl[idx] = lo;
  }
}

// ---------------------------------------------------------------------------
// gemm_nb — NO-LDS, NO-BARRIER in_proj GEMM.  Block 256 thr = 4 free-running
// waves; wave wn owns cols n0+wn*32 (2x16), all 64 rows of the block's tile.
// All MFMA operands loaded DIRECTLY from global pre-split planes in fragment
// layout (lane lr: row m0+mf*16+lr; k = kb+kc*32+lq*8 -> one 16B load).
// A block (48 KB x 3 planes) is L1/L2-resident across the 4-wave x 4-panel
// re-reads.  MFMA per-accumulator op order identical -> bit-identical C.
// ---------------------------------------------------------------------------
__global__ __launch_bounds__(256) void gemm_nb(
    const u16* __restrict__ Ah, const u16* __restrict__ Am,
    const u16* __restrict__ Al, int lda,
    const u16* __restrict__ Wh, const u16* __restrict__ Wm,
    const u16* __restrict__ Wl,
    float* __restrict__ C, int ldc, int N, int K) {
  const int m0 = blockIdx.x * 64;
  const int n0 = blockIdx.y * 128;
  const int tid = threadIdx.x;
  const int lane = tid & 63;
  const int wn = tid >> 6;
  const int lr = lane & 15;
  const int lq = lane >> 4;

  f32x4 a0[4][2], a1[4][2], a2[4][2];
  const f32x4 zz = {0.f, 0.f, 0.f, 0.f};
#pragma unroll
  for (int i = 0; i < 4; ++i)
#pragma unroll
    for (int j = 0; j < 2; ++j) { a0[i][j] = zz; a1[i][j] = zz; a2[i][j] = zz; }

  const int col0 = n0 + wn * 32 + lr;
  const int col1 = col0 + 16;
  const int c0 = col0 < N ? col0 : N - 1;
  const int c1 = col1 < N ? col1 : N - 1;
  const size_t bo0 = (size_t)c0 * K + lq * 8;
  const size_t bo1 = (size_t)c1 * K + lq * 8;
  // per-lane A fragment base: row m0+lr (mf adds 16 rows), col lq*8
  const size_t ao = (size_t)(m0 + lr) * lda + lq * 8;

  for (int kb = 0; kb < K; kb += 64) {
    // B fragments for this k-tile (12 x 16B, independent)
    s16x8 bh0[2], bh1[2], bm0[2], bm1[2], bl0[2], bl1[2];
#pragma unroll
    for (int kc = 0; kc < 2; ++kc) {
      const int ko = kb + kc * 32;
      bh0[kc] = *(const s16x8*)(Wh + bo0 + ko);
      bh1[kc] = *(const s16x8*)(Wh + bo1 + ko);
      bm0[kc] = *(const s16x8*)(Wm + bo0 + ko);
      bm1[kc] = *(const s16x8*)(Wm + bo1 + ko);
      bl0[kc] = *(const s16x8*)(Wl + bo0 + ko);
      bl1[kc] = *(const s16x8*)(Wl + bo1 + ko);
    }
#pragma unroll
    for (int mf = 0; mf < 4; ++mf) {
      const size_t ar = ao + (size_t)(mf * 16) * lda + kb;
#pragma unroll
      for (int kc = 0; kc < 2; ++kc) {
        const s16x8 ah = *(const s16x8*)(Ah + ar + kc * 32);
        const s16x8 am = *(const s16x8*)(Am + ar + kc * 32);
        const s16x8 al = *(const s16x8*)(Al + ar + kc * 32);
        a0[mf][0] = mfma_bf(ah, bh0[kc], a0[mf][0]);
        a0[mf][1] = mfma_bf(ah, bh1[kc], a0[mf][1]);
        a1[mf][0] = mfma_bf(ah, bm0[kc], a1[mf][0]);
        a1[mf][1] = mfma_bf(ah, bm1[kc], a1[mf][1]);
        a1[mf][0] = mfma_bf(am, bh0[kc], a1[mf][0]);
        a1[mf][1] = mfma_bf(am, bh1[kc], a1[mf][1]);
        a2[mf][0] = mfma_bf(ah, bl0[kc], a2[mf][0]);
        a2[mf][1] = mfma_bf(ah, bl1[kc], a2[mf][1]);
        a2[mf][0] = mfma_bf(al, bh0[kc], a2[mf][0]);
        a2[mf][1] = mfma_bf(al, bh1[kc], a2[mf][1]);
        a2[mf][0] = mfma_bf(am, bm0[kc], a2[mf][0]);
        a2[mf][1] = mfma_bf(am, bm1[kc], a2[mf][1]);
      }
    }
  }
#pragma unroll
  for (int mf = 0; mf < 4; ++mf) {
#pragma unroll
    for (int nf = 0; nf < 2; ++nf) {
      const int col = n0 + wn * 32 + nf * 16 + lr;
      if (col < N) {
#pragma unroll
        for (int r = 0; r < 4; ++r) {
          const int row = m0 + mf * 16 + lq * 4 + r;
          C[(size_t)row * ldc + col] =
              fmaf(C8, fmaf(C8, a2[mf][nf][r], a1[mf][nf][r]), a0[mf][nf][r]);
        }
      }
    }
  }
}

// ---------------------------------------------------------------------------
// gemm_pl — pipelined plain-A 3-split GEMM (R12-proven), used for out_proj.
// Optionally also emits 3 bf16 planes of C (for the next layer's in_proj).
// ---------------------------------------------------------------------------
__global__ __launch_bounds__(256) void gemm_pl(
    const float* __restrict__ A, int lda,
    const u16* __restrict__ Wh, const u16* __restrict__ Wm,
    const u16* __restrict__ Wl,
    float* __restrict__ C, u16* __restrict__ Ch, u16* __restrict__ Cm,
    u16* __restrict__ Cl, int ldc, int N, int K) {
  __shared__ __align__(16) u16 Lh[64 * 72];
  __shared__ __align__(16) u16 Lm[64 * 72];
  __shared__ __align__(16) u16 Lo[64 * 72];
  const int m0 = blockIdx.x * 64;
  const int n0 = blockIdx.y * 128;
  const int tid = threadIdx.x;
  const int lane = tid & 63;
  const int wn = tid >> 6;
  const int lr = lane & 15;
  const int lq = lane >> 4;

  f32x4 a0[4][2], a1[4][2], a2[4][2];
  const f32x4 zz = {0.f, 0.f, 0.f, 0.f};
#pragma unroll
  for (int i = 0; i < 4; ++i)
#pragma unroll
    for (int j = 0; j < 2; ++j) { a0[i][j] = zz; a1[i][j] = zz; a2[i][j] = zz; }

  const int col0 = n0 + wn * 32 + lr;
  const int col1 = col0 + 16;
  const int c0 = col0 < N ? col0 : N - 1;
  const int c1 = col1 < N ? col1 : N - 1;
  const size_t bo0 = (size_t)c0 * K + lq * 8;
  const size_t bo1 = (size_t)c1 * K + lq * 8;

  const int srow = tid >> 2;
  const int sg = (tid & 3) * 16;
  const int sdst = srow * 72 + sg;
  const int grow = m0 + srow;

  float v[16];
  auto load_a = [&](int kb) {
    const float* pa = A + (size_t)grow * lda + kb + sg;
#pragma unroll
    for (int q = 0; q < 4; ++q) {
      float4 a = *(const float4*)(pa + q * 4);
      v[q * 4 + 0] = a.x; v[q * 4 + 1] = a.y;
      v[q * 4 + 2] = a.z; v[q * 4 + 3] = a.w;
    }
  };

  const int T = K / 64;
  load_a(0);
  for (int t = 0; t < T; ++t) {
    const int kb = t * 64;
    s16x8 bh0[2], bh1[2], bm0[2], bm1[2], bl0[2], bl1[2];
#pragma unroll
    for (int kc = 0; kc < 2; ++kc) {
      const int ko = kb + kc * 32;
      bh0[kc] = *(const s16x8*)(Wh + bo0 + ko);
      bh1[kc] = *(const s16x8*)(Wh + bo1 + ko);
      bm0[kc] = *(const s16x8*)(Wm + bo0 + ko);
      bm1[kc] = *(const s16x8*)(Wm + bo1 + ko);
      bl0[kc] = *(const s16x8*)(Wl + bo0 + ko);
      bl1[kc] = *(const s16x8*)(Wl + bo1 + ko);
    }
    s16x8 h8a, m8a, l8a, h8b, m8b, l8b;
#pragma unroll
    for (int j = 0; j < 8; ++j) {
      u16 h, m, l;
      split3(v[j], h, m, l);
      h8a[j] = (short)h; m8a[j] = (short)m; l8a[j] = (short)l;
    }
#pragma unroll
    for (int j = 0; j < 8; ++j) {
      u16 h, m, l;
      split3(v[8 + j], h, m, l);
      h8b[j] = (short)h; m8b[j] = (short)m; l8b[j] = (short)l;
    }
    *(s16x8*)&Lh[sdst] = h8a; *(s16x8*)&Lh[sdst + 8] = h8b;
    *(s16x8*)&Lm[sdst] = m8a; *(s16x8*)&Lm[sdst + 8] = m8b;
    *(s16x8*)&Lo[sdst] = l8a; *(s16x8*)&Lo[sdst + 8] = l8b;
    __syncthreads();
    if (t + 1 < T) load_a(kb + 64);
#pragma unroll
    for (int kc = 0; kc < 2; ++kc) {
#pragma unroll
      for (int mf = 0; mf < 4; ++mf) {
        const int ar = (mf * 16 + lr) * 72 + kc * 32 + lq * 8;
        const s16x8 ah = *(const s16x8*)&Lh[ar];
        const s16x8 am = *(const s16x8*)&Lm[ar];
        const s16x8 al = *(const s16x8*)&Lo[ar];
        a0[mf][0] = mfma_bf(ah, bh0[kc], a0[mf][0]);
        a0[mf][1] = mfma_bf(ah, bh1[kc], a0[mf][1]);
        a1[mf][0] = mfma_bf(ah, bm0[kc], a1[mf][0]);
        a1[mf][1] = mfma_bf(ah, bm1[kc], a1[mf][1]);
        a1[mf][0] = mfma_bf(am, bh0[kc], a1[mf][0]);
        a1[mf][1] = mfma_bf(am, bh1[kc], a1[mf][1]);
        a2[mf][0] = mfma_bf(ah, bl0[kc], a2[mf][0]);
        a2[mf][1] = mfma_bf(ah, bl1[kc], a2[mf][1]);
        a2[mf][0] = mfma_bf(al, bh0[kc], a2[mf][0]);
        a2[mf][1] = mfma_bf(al, bh1[kc], a2[mf][1]);
        a2[mf][0] = mfma_bf(am, bm0[kc], a2[mf][0]);
        a2[mf][1] = mfma_bf(am, bm1[kc], a2[mf][1]);
      }
    }
    __syncthreads();
  }
#pragma unroll
  for (int mf = 0; mf < 4; ++mf) {
#pragma unroll
    for (int nf = 0; nf < 2; ++nf) {
      const int col = n0 + wn * 32 + nf * 16 + lr;
      if (col < N) {
#pragma unroll
        for (int r = 0; r < 4; ++r) {
          const int row = m0 + mf * 16 + lq * 4 + r;
          const float val =
              fmaf(C8, fmaf(C8, a2[mf][nf][r], a1[mf][nf][r]), a0[mf][nf][r]);
          C[(size_t)row * ldc + col] = val;
          if (Ch) {
            u16 h, m, lo;
            split3(val, h, m, lo);
            Ch[(size_t)row * ldc + col] = h;
            Cm[(size_t)row * ldc + col] = m;
            Cl[(size_t)row * ldc + col] = lo;
          }
        }
      }
    }
  }
}

// ---------------------------------------------------------------------------
// gemm_fc — fused conv+silu x_proj GEMM (R8/R12-proven)
// ---------------------------------------------------------------------------
__global__ __launch_bounds__(256) void gemm_fc(
    const float* __restrict__ A,
    const float* __restrict__ cw, const float* __restrict__ cb,
    const u16* __restrict__ Wh, const u16* __restrict__ Wm,
    const u16* __restrict__ Wl,
    float* __restrict__ C, int ldc, int N, int K) {
  __shared__ __align__(16) u16 Lh[64 * 40];
  __shared__ __align__(16) u16 Lm[64 * 40];
  __shared__ __align__(16) u16 Lo[64 * 40];
  const int m0 = blockIdx.x * 64;
  const int n0 = blockIdx.y * 128;
  const int tid = threadIdx.x;
  const int lane = tid & 63;
  const int wn = tid >> 6;
  const int lr = lane & 15;
  const int lq = lane >> 4;

  f32x4 a0[4][2], a1[4][2], a2[4][2];
  const f32x4 zz = {0.f, 0.f, 0.f, 0.f};
#pragma unroll
  for (int i = 0; i < 4; ++i)
#pragma unroll
    for (int j = 0; j < 2; ++j) { a0[i][j] = zz; a1[i][j] = zz; a2[i][j] = zz; }

  const int col0 = n0 + wn * 32 + lr;
  const int col1 = col0 + 16;
  const int c0 = col0 < N ? col0 : N - 1;
  const int c1 = col1 < N ? col1 : N - 1;
  const size_t bo0 = (size_t)c0 * K + lq * 8;
  const size_t bo1 = (size_t)c1 * K + lq * 8;

  const int srow = tid >> 2;
  const int sg = (tid & 3) * 8;
  const int sdst = srow * 40 + sg;
  const int grow = m0 + srow;

  for (int k0 = 0; k0 < K; k0 += 32) {
    float v[8];
    {
      const int l = grow & (Ll - 1);
      const float* px = A + (size_t)grow * 512 + k0 + sg;
      const float4 z4 = make_float4(0.f, 0.f, 0.f, 0.f);
      float4 r0a = *(const float4*)px;
      float4 r0b = *(const float4*)(px + 4);
      float4 r1a = z4, r1b = z4, r2a = z4, r2b = z4, r3a = z4, r3b = z4;
      if (l >= 1) { r1a = *(const float4*)(px - 512);  r1b = *(const float4*)(px - 508); }
      if (l >= 2) { r2a = *(const float4*)(px - 1024); r2b = *(const float4*)(px - 1020); }
      if (l >= 3) { r3a = *(const float4*)(px - 1536); r3b = *(const float4*)(px - 1532); }
      const float* cwp = cw + (size_t)(k0 + sg) * 4;
      const float4 w0 = *(const float4*)(cwp + 0);
      const float4 w1 = *(const float4*)(cwp + 4);
      const float4 w2 = *(const float4*)(cwp + 8);
      const float4 w3 = *(const float4*)(cwp + 12);
      const float4 w4 = *(const float4*)(cwp + 16);
      const float4 w5 = *(const float4*)(cwp + 20);
      const float4 w6 = *(const float4*)(cwp + 24);
      const float4 w7 = *(const float4*)(cwp + 28);
      const float4 cba = *(const float4*)(cb + k0 + sg);
      const float4 cbb = *(const float4*)(cb + k0 + sg + 4);
      v[0] = conv_u(r3a.x, r2a.x, r1a.x, r0a.x, w0, cba.x);
      v[1] = conv_u(r3a.y, r2a.y, r1a.y, r0a.y, w1, cba.y);
      v[2] = conv_u(r3a.z, r2a.z, r1a.z, r0a.z, w2, cba.z);
      v[3] = conv_u(r3a.w, r2a.w, r1a.w, r0a.w, w3, cba.w);
      v[4] = conv_u(r3b.x, r2b.x, r1b.x, r0b.x, w4, cbb.x);
      v[5] = conv_u(r3b.y, r2b.y, r1b.y, r0b.y, w5, cbb.y);
      v[6] = conv_u(r3b.z, r2b.z, r1b.z, r0b.z, w6, cbb.z);
      v[7] = conv_u(r3b.w, r2b.w, r1b.w, r0b.w, w7, cbb.w);
    }
    s16x8 h8, m8, l8;
#pragma unroll
    for (int j = 0; j < 8; ++j) {
      u16 h, m, l;
      split3(v[j], h, m, l);
      h8[j] = (short)h; m8[j] = (short)m; l8[j] = (short)l;
    }
    *(s16x8*)&Lh[sdst] = h8;
    *(s16x8*)&Lm[sdst] = m8;
    *(s16x8*)&Lo[sdst] = l8;
    __syncthreads();
    const s16x8 bh0 = *(const s16x8*)(Wh + bo0 + k0);
    const s16x8 bh1 = *(const s16x8*)(Wh + bo1 + k0);
    const s16x8 bm0 = *(const s16x8*)(Wm + bo0 + k0);
    const s16x8 bm1 = *(const s16x8*)(Wm + bo1 + k0);
    const s16x8 bl0 = *(const s16x8*)(Wl + bo0 + k0);
    const s16x8 bl1 = *(const s16x8*)(Wl + bo1 + k0);
#pragma unroll
    for (int mf = 0; mf < 4; ++mf) {
      const int ar = (mf * 16 + lr) * 40 + lq * 8;
      const s16x8 ah = *(const s16x8*)&Lh[ar];
      const s16x8 am = *(const s16x8*)&Lm[ar];
      const s16x8 al = *(const s16x8*)&Lo[ar];
      a0[mf][0] = mfma_bf(ah, bh0, a0[mf][0]);
      a1[mf][0] = mfma_bf(ah, bm0, a1[mf][0]);
      a1[mf][0] = mfma_bf(am, bh0, a1[mf][0]);
      a2[mf][0] = mfma_bf(ah, bl0, a2[mf][0]);
      a2[mf][0] = mfma_bf(al, bh0, a2[mf][0]);
      a2[mf][0] = mfma_bf(am, bm0, a2[mf][0]);
      a0[mf][1] = mfma_bf(ah, bh1, a0[mf][1]);
      a1[mf][1] = mfma_bf(ah, bm1, a1[mf][1]);
      a1[mf][1] = mfma_bf(am, bh1, a1[mf][1]);
      a2[mf][1] = mfma_bf(ah, bl1, a2[mf][1]);
      a2[mf][1] = mfma_bf(al, bh1, a2[mf][1]);
      a2[mf][1] = mfma_bf(am, bm1, a2[mf][1]);
    }
    __syncthreads();
  }
#pragma unroll
  for (int mf = 0; mf < 4; ++mf) {
#pragma unroll
    for (int nf = 0; nf < 2; ++nf) {
      const int col = n0 + wn * 32 + nf * 16 + lr;
      if (col < N) {
#pragma unroll
        for (int r = 0; r < 4; ++r) {
          const int row = m0 + mf * 16 + lq * 4 + r;
          C[(size_t)row * ldc + col] =
              fmaf(C8, fmaf(C8, a2[mf][nf][r], a1[mf][nf][r]), a0[mf][nf][r]);
        }
      }
    }
  }
}

// ---------------------------------------------------------------------------
// Selective scan (R12-proven; u on-the-fly via rolling 4-window)
// ---------------------------------------------------------------------------
#define LOAD_A2(base)                                                        \
  float4 a2a = *(const float4*)((base));                                     \
  float4 a2b = *(const float4*)((base) + 4);                                 \
  float4 a2c = *(const float4*)((base) + 8);                                 \
  float4 a2d = *(const float4*)((base) + 12);                                \
  a2a.x = -expf(a2a.x) * LOG2E; a2a.y = -expf(a2a.y) * LOG2E;                \
  a2a.z = -expf(a2a.z) * LOG2E; a2a.w = -expf(a2a.w) * LOG2E;                \
  a2b.x = -expf(a2b.x) * LOG2E; a2b.y = -expf(a2b.y) * LOG2E;                \
  a2b.z = -expf(a2b.z) * LOG2E; a2b.w = -expf(a2b.w) * LOG2E;                \
  a2c.x = -expf(a2c.x) * LOG2E; a2c.y = -expf(a2c.y) * LOG2E;                \
  a2c.z = -expf(a2c.z) * LOG2E; a2c.w = -expf(a2c.w) * LOG2E;                \
  a2d.x = -expf(a2d.x) * LOG2E; a2d.y = -expf(a2d.y) * LOG2E;                \
  a2d.z = -expf(a2d.z) * LOG2E; a2d.w = -expf(a2d.w) * LOG2E;

#define DT_FROM_Q(q0, q1, w0, w1, dtbv)                                      \
  float dtr = (dtbv);                                                        \
  dtr = fmaf((q0).x, (w0).x, dtr); dtr = fmaf((q0).y, (w0).y, dtr);          \
  dtr = fmaf((q0).z, (w0).z, dtr); dtr = fmaf((q0).w, (w0).w, dtr);          \
  dtr = fmaf((q1).x, (w1).x, dtr); dtr = fmaf((q1).y, (w1).y, dtr);          \
  dtr = fmaf((q1).z, (w1).z, dtr); dtr = fmaf((q1).w, (w1).w, dtr);

#define UPD1(H, A, Bv)                                                       \
  (H).x = fmaf(hexp2(sp * (A).x), (H).x, dtu * (Bv).x);                      \
  (H).y = fmaf(hexp2(sp * (A).y), (H).y, dtu * (Bv).y);                      \
  (H).z = fmaf(hexp2(sp * (A).z), (H).z, dtu * (Bv).z);                      \
  (H).w = fmaf(hexp2(sp * (A).w), (H).w, dtu * (Bv).w);

#define UPD3(H, A, Bv, Cv)                                                   \
  (H).x = fmaf(hexp2(sp * (A).x), (H).x, dtu * (Bv).x);                      \
  y = fmaf((H).x, (Cv).x, y);                                                \
  (H).y = fmaf(hexp2(sp * (A).y), (H).y, dtu * (Bv).y);                      \
  y = fmaf((H).y, (Cv).y, y);                                                \
  (H).z = fmaf(hexp2(sp * (A).z), (H).z, dtu * (Bv).z);                      \
  y = fmaf((H).z, (Cv).z, y);                                                \
  (H).w = fmaf(hexp2(sp * (A).w), (H).w, dtu * (Bv).w);                      \
  y = fmaf((H).w, (Cv).w, y);

__global__ __launch_bounds__(256) void k_scan_ph1(
    const float* __restrict__ xz, const float* __restrict__ dbl,
    const float* __restrict__ cw, const float* __restrict__ cb,
    const float* __restrict__ dtw, const float* __restrict__ dtb,
    const float* __restrict__ alog, float* __restrict__ hloc,
    float* __restrict__ sdtc) {
  const int b = blockIdx.x / NC;
  const int c = blockIdx.x % NC;
  const int d = threadIdx.x;
  LOAD_A2(alog + d * 16)
  const float4 w0 = *(const float4*)(dtw + d * 8);
  const float4 w1 = *(const float4*)(dtw + d * 8 + 4);
  const float dtbv = dtb[d];
  const float4 cwd = *(const float4*)(cw + d * 4);
  const float cbd = cb[d];
  float4 ha = make_float4(0.f, 0.f, 0.f, 0.f);
  float4 hb = ha, hc = ha, hd = ha;
  float sdt = 0.f;
  const float* xb = xz + (size_t)b * Ll * 512 + d;
  const float* db = dbl + (size_t)b * Ll * 40;
  const int l0 = c * CL;
  float x3 = l0 >= 3 ? xb[(size_t)(l0 - 3) * 512] : 0.f;
  float x2 = l0 >= 2 ? xb[(size_t)(l0 - 2) * 512] : 0.f;
  float x1 = l0 >= 1 ? xb[(size_t)(l0 - 1) * 512] : 0.f;
  for (int l = l0; l < l0 + CL; ++l) {
    const float x0 = xb[(size_t)l * 512];
    const float uv = conv_u(x3, x2, x1, x0, cwd, cbd);
    x3 = x2; x2 = x1; x1 = x0;
    const float* dr = db + (size_t)l * 40;
    const float4 q0 = *(const float4*)(dr);
    const float4 q1 = *(const float4*)(dr + 4);
    const float4 bfa = *(const float4*)(dr + 8);
    const float4 bfb = *(const float4*)(dr + 12);
    const float4 bfc = *(const float4*)(dr + 16);
    const float4 bfd = *(const float4*)(dr + 20);
    DT_FROM_Q(q0, q1, w0, w1, dtbv)
    const float sp = softplus_f(dtr);
    sdt += sp;
    const float dtu = sp * uv;
    UPD1(ha, a2a, bfa)
    UPD1(hb, a2b, bfb)
    UPD1(hc, a2c, bfc)
    UPD1(hd, a2d, bfd)
  }
  const size_t o = (size_t)(b * NC + c) * 256 + d;
  *(float4*)(hloc + o * 16 + 0)  = ha;
  *(float4*)(hloc + o * 16 + 4)  = hb;
  *(float4*)(hloc + o * 16 + 8)  = hc;
  *(float4*)(hloc + o * 16 + 12) = hd;
  sdtc[o] = sdt;
}

__global__ __launch_bounds__(256) void k_scan_ph2(
    const float* __restrict__ alog, float* __restrict__ hloc,
    const float* __restrict__ sdtc) {
  const int b = blockIdx.x >> 4;
  const int dg = blockIdx.x & 15;
  const int d = dg * 16 + (threadIdx.x >> 4);
  const int s = threadIdx.x & 15;
  const float A2 = -expf(alog[d * 16 + s]) * LOG2E;
  float hs = 0.f;
  for (int c = 0; c < NC; ++c) {
    const size_t o = (size_t)(b * NC + c) * 256 + d;
    const float tmp = hloc[o * 16 + s];
    hloc[o * 16 + s] = hs;
    hs = fmaf(hexp2(A2 * sdtc[o]), hs, tmp);
  }
}

__global__ __launch_bounds__(256) void k_scan_ph3(
    const float* __restrict__ xz, const float* __restrict__ dbl,
    const float* __restrict__ cw, const float* __restrict__ cb,
    const float* __restrict__ dtw, const float* __restrict__ dtb,
    const float* __restrict__ alog, const float* __restrict__ Dv,
    const float* __restrict__ hstart, float* __restrict__ ybuf) {
  const int b = blockIdx.x / NC;
  const int c = blockIdx.x % NC;
  const int d = threadIdx.x;
  LOAD_A2(alog + d * 16)
  const float4 w0 = *(const float4*)(dtw + d * 8);
  const float4 w1 = *(const float4*)(dtw + d * 8 + 4);
  const float dtbv = dtb[d];
  const float Dd = Dv[d];
  const float4 cwd = *(const float4*)(cw + d * 4);
  const float cbd = cb[d];
  const size_t o = (size_t)(b * NC + c) * 256 + d;
  float4 ha = *(const float4*)(hstart + o * 16 + 0);
  float4 hb = *(const float4*)(hstart + o * 16 + 4);
  float4 hc = *(const float4*)(hstart + o * 16 + 8);
  float4 hd = *(const float4*)(hstart + o * 16 + 12);
  const float* xb = xz + (size_t)b * Ll * 512 + d;
  const float* db = dbl + (size_t)b * Ll * 40;
  float* yb = ybuf + (size_t)b * Ll * 256 + d;
  const int l0 = c * CL;
  float x3 = l0 >= 3 ? xb[(size_t)(l0 - 3) * 512] : 0.f;
  float x2 = l0 >= 2 ? xb[(size_t)(l0 - 2) * 512] : 0.f;
  float x1 = l0 >= 1 ? xb[(size_t)(l0 - 1) * 512] : 0.f;
  for (int l = l0; l < l0 + CL; ++l) {
    const float x0 = xb[(size_t)l * 512];
    const float uv = conv_u(x3, x2, x1, x0, cwd, cbd);
    x3 = x2; x2 = x1; x1 = x0;
    const float* dr = db + (size_t)l * 40;
    const float4 q0 = *(const float4*)(dr);
    const float4 q1 = *(const float4*)(dr + 4);
    const float4 bfa = *(const float4*)(dr + 8);
    const float4 bfb = *(const float4*)(dr + 12);
    const float4 bfc = *(const float4*)(dr + 16);
    const float4 bfd = *(const float4*)(dr + 20);
    const float4 cfa = *(const float4*)(dr + 24);
    const float4 cfb = *(const float4*)(dr + 28);
    const float4 cfc = *(const float4*)(dr + 32);
    const float4 cfd = *(const float4*)(dr + 36);
    DT_FROM_Q(q0, q1, w0, w1, dtbv)
    const float sp = softplus_f(dtr);
    const float dtu = sp * uv;
    float y = 0.f;
    UPD3(ha, a2a, bfa, cfa)
    UPD3(hb, a2b, bfb, cfb)
    UPD3(hc, a2c, bfc, cfc)
    UPD3(hd, a2d, bfd, cfd)
    y = fmaf(uv, Dd, y);
    const float zv = xb[(size_t)l * 512 + 256];
    yb[(size_t)l * 256] = y * (zv * sigmoid_f(zv));
  }
}

// ---------------------------------------------------------------------------
// Pooling, two-stage
// ---------------------------------------------------------------------------
__global__ __launch_bounds__(128) void k_pool_part(const float* __restrict__ x,
                                                   float* __restrict__ part) {
  const int b = blockIdx.x >> 5;
  const int c = blockIdx.x & 31;
  const int m = threadIdx.x;
  const float* xb = x + (size_t)b * Ll * 128 + (size_t)c * 128 * 128 + m;
  float s = 0.f;
#pragma unroll 4
  for (int l = 0; l < 128; ++l) s += xb[(size_t)l * 128];
  part[(size_t)blockIdx.x * 128 + m] = s;
}

__global__ __launch_bounds__(128) void k_pool_fin(const float* __restrict__ part,
                                                  float* __restrict__ out) {
  const int b = blockIdx.x, m = threadIdx.x;
  float p = 0.f;
#pragma unroll
  for (int c = 0; c < 32; ++c) p += part[((size_t)b * 32 + c) * 128 + m];
  p *= (1.f / Ll);
  __shared__ float pm[128];
  __shared__ float sq[128];
  pm[m] = p;
  sq[m] = p * p;
  __syncthreads();
  for (int wd = 64; wd >= 1; wd >>= 1) {
    if (m < wd) sq[m] += sq[m + wd];
    __syncthreads();
  }
  out[b * 128 + m] = pm[m] / fmaxf(sqrtf(sq[0]), 1e-12f);
}

// ---------------------------------------------------------------------------
extern "C" void kernel_launch(void* const* d_in, const int* in_sizes, int n_in,
                              void* d_out, int out_size, void* d_ws, size_t ws_size,
                              hipStream_t stream) {
  (void)in_sizes; (void)n_in; (void)out_size; (void)ws_size;
  const float* t    = (const float*)d_in[0];
  const float* embw = (const float*)d_in[1];
  const float* inw  = (const float*)d_in[2];
  const float* cw   = (const float*)d_in[3];
  const float* cb   = (const float*)d_in[4];
  const float* xpw  = (const float*)d_in[5];
  const float* dtw  = (const float*)d_in[6];
  const float* dtb  = (const float*)d_in[7];
  const float* alog = (const float*)d_in[8];
  const float* Dv   = (const float*)d_in[9];
  const float* ow   = (const float*)d_in[10];

  float* wsf  = (float*)d_ws;
  float* xz   = wsf;                   // (B,L,512)      16777216 f
  float* xb   = xz + 16777216;         // (B,L,128)       4194304 f
  float* ybuf = xb + 4194304;          // (B,L,256)       8388608 f
  float* dblb = ybuf + 8388608;        // (B,L,40)        1310720 f
  float* hloc = dblb + 1310720;        // (B,NC,256,16)   4194304 f
  float* sdtc = hloc + 4194304;        // (B,NC,256)       262144 f
  float* pool = sdtc + 262144;         // (B,32,128)        32768 f
  u16* xbh = (u16*)(pool + 32768);     // (B,L,128) halves = 2097152 f
  u16* xbm = (u16*)(pool + 32768 + 2097152);
  u16* xbl = (u16*)(pool + 32768 + 4194304);
  float* wtb = pool + 32768 + 6291456; // bf16 weight planes
  u16* wih = (u16*)(wtb);
  u16* wim = (u16*)(wtb + 65536);
  u16* wil = (u16*)(wtb + 131072);
  u16* wxh = (u16*)(wtb + 196608);
  u16* wxm = (u16*)(wtb + 206848);
  u16* wxl = (u16*)(wtb + 217088);
  u16* woh = (u16*)(wtb + 227328);
  u16* wom = (u16*)(wtb + 260096);
  u16* wol = (u16*)(wtb + 292864);
  float* outp = (float*)d_out;

  k_split3<<<dim3(512), 256, 0, stream>>>(inw, wih, wim, wil, 131072);
  k_split3<<<dim3(80),  256, 0, stream>>>(xpw, wxh, wxm, wxl, 20480);
  k_split3<<<dim3(256), 256, 0, stream>>>(ow,  woh, wom, wol, 65536);

  // embed writes xb as 3 bf16 planes (producer-side split)
  k_embed<<<dim3(Bb * (Ll / 32)), dim3(128), 0, stream>>>(t, embw, xbh, xbm, xbl);

  for (int layer = 0; layer < 2; ++layer) {
    const u16* wih_l = wih + (size_t)layer * 512 * 128;
    const u16* wim_l = wim + (size_t)layer * 512 * 128;
    const u16* wil_l = wil + (size_t)layer * 512 * 128;
    const u16* wxh_l = wxh + (size_t)layer * 40 * 256;
    const u16* wxm_l = wxm + (size_t)layer * 40 * 256;
    const u16* wxl_l = wxl + (size_t)layer * 40 * 256;
    const u16* woh_l = woh + (size_t)layer * 128 * 256;
    const u16* wom_l = wom + (size_t)layer * 128 * 256;
    const u16* wol_l = wol + (size_t)layer * 128 * 256;
    const float* cw_l  = cw + layer * 256 * 4;
    const float* cb_l  = cb + layer * 256;
    const float* dtw_l = dtw + layer * 256 * 8;
    const float* dtb_l = dtb + layer * 256;
    const float* al_l  = alog + layer * 256 * 16;
    const float* D_l   = Dv + layer * 256;

    // in_proj: (M=32768, N=512, K=128) -> xz fp32  [no-LDS no-barrier direct]
    gemm_nb<<<dim3(Mrows / 64, 4), 256, 0, stream>>>(
        xbh, xbm, xbl, 128, wih_l, wim_l, wil_l, xz, 512, 512, 128);
    // x_proj fused conv+silu: (N=40, K=256) -> dbl fp32
    gemm_fc<<<dim3(Mrows / 64, 1), 256, 0, stream>>>(
        xz, cw_l, cb_l, wxh_l, wxm_l, wxl_l, dblb, 40, 40, 256);
    // chunked selective scan (u on-the-fly from xz)
    k_scan_ph1<<<dim3(Bb * NC), 256, 0, stream>>>(xz, dblb, cw_l, cb_l,
                                                  dtw_l, dtb_l, al_l, hloc, sdtc);
    k_scan_ph2<<<dim3(Bb * 16), 256, 0, stream>>>(al_l, hloc, sdtc);
    k_scan_ph3<<<dim3(Bb * NC), 256, 0, stream>>>(xz, dblb, cw_l, cb_l,
                                                  dtw_l, dtb_l, al_l, D_l,
                                                  hloc, ybuf);
    // out_proj: (N=128, K=256) -> xb fp32 + next-layer planes
    gemm_pl<<<dim3(Mrows / 64, 1), 256, 0, stream>>>(
        ybuf, 256, woh_l, wom_l, wol_l, xb, xbh, xbm, xbl, 128, 128, 256);
  }

  k_pool_part<<<dim3(Bb * 32), 128, 0, stream>>>(xb, pool);
  k_pool_fin<<<dim3(Bb), 128, 0, stream>>>(pool, outp);
}

// Round 17
// 402.429 us; speedup vs baseline: 1.1663x; 1.1663x over previous
//
#include <hip/hip_runtime.h>
#include <cmath>

#define LOG2E 1.4426950408889634f
#define LN2   0.6931471805599453f
#define C8    0.00390625f   // 2^-8

constexpr int Bb = 8;
constexpr int Ll = 4096;
constexpr int Mrows = Bb * Ll;      // 32768
constexpr int NC = 128;             // chunks per sequence
constexpr int CL = Ll / NC;         // 32 steps per chunk

typedef unsigned short u16;
typedef short s16x8 __attribute__((ext_vector_type(8)));
typedef float f32x4 __attribute__((ext_vector_type(4)));

__device__ __forceinline__ float hexp2(float x) { return __builtin_amdgcn_exp2f(x); }
__device__ __forceinline__ float hlog2(float x) { return __builtin_amdgcn_logf(x); }
__device__ __forceinline__ float hrcp(float x)  { return __builtin_amdgcn_rcpf(x); }

__device__ __forceinline__ float softplus_f(float x) {
  const float t = hexp2(-fabsf(x) * LOG2E);
  return fmaxf(x, 0.f) + LN2 * hlog2(1.f + t);
}
__device__ __forceinline__ float sigmoid_f(float x) {
  return hrcp(1.f + hexp2(-x * LOG2E));
}
// causal depthwise conv (k=4) + bias + silu — exact op order (bit-identical u)
__device__ __forceinline__ float conv_u(float x3, float x2, float x1, float x0,
                                        float4 w, float bias) {
  float acc = 0.f;
  acc = fmaf(x3, w.x, acc);
  acc = fmaf(x2, w.y, acc);
  acc = fmaf(x1, w.z, acc);
  acc = fmaf(x0, w.w, acc);
  acc += bias;
  return acc * sigmoid_f(acc);
}

__device__ __forceinline__ f32x4 mfma_bf(s16x8 a, s16x8 b, f32x4 c) {
  return __builtin_amdgcn_mfma_f32_16x16x32_bf16(a, b, c, 0, 0, 0);
}

// bf16 RNE; 3-plane split is EXACT for fp32 (24-bit mantissa = 3x8)
__device__ __forceinline__ u16 bf16rne(float v) {
  unsigned u = __float_as_uint(v);
  u += 0x7FFFu + ((u >> 16) & 1u);
  return (u16)(u >> 16);
}
__device__ __forceinline__ float bf2f(u16 h) {
  return __uint_as_float(((unsigned)h) << 16);
}
__device__ __forceinline__ void split3(float v, u16& h, u16& m, u16& l) {
  h = bf16rne(v);
  const float r1 = (v - bf2f(h)) * 256.f;
  m = bf16rne(r1);
  const float r2 = (r1 - bf2f(m)) * 256.f;
  l = bf16rne(r2);
}

// ---------------------------------------------------------------------------
__global__ __launch_bounds__(256) void k_split3(const float* __restrict__ src,
                                                u16* __restrict__ h,
                                                u16* __restrict__ m,
                                                u16* __restrict__ l, int n) {
  const int i = blockIdx.x * 256 + threadIdx.x;
  if (i < n) {
    u16 a, b, c;
    split3(src[i], a, b, c);
    h[i] = a; m[i] = b; l[i] = c;
  }
}

// ---------------------------------------------------------------------------
__global__ __launch_bounds__(128) void k_embed(const float* __restrict__ t,
                                               const float* __restrict__ w,
                                               float* __restrict__ x) {
  __shared__ float ws[128 * 27];
  const int d = threadIdx.x;
  for (int i = d; i < 128 * 27; i += 128) ws[i] = w[i];
  __syncthreads();
  const int bpb = Ll / 32;
  const int b = blockIdx.x / bpb;
  const int l0 = (blockIdx.x % bpb) * 32;
  const float* wd = &ws[d * 27];
  for (int l = l0; l < l0 + 32; ++l) {
    float acc = 0.f;
#pragma unroll
    for (int k = 0; k < 3; ++k) {
      int li = l + k - 1;
      if (li < 0) li += Ll;
      if (li >= Ll) li -= Ll;
      const float* tr = t + ((size_t)b * Ll + li) * 9;
#pragma unroll
      for (int c = 0; c < 9; ++c) acc = fmaf(tr[c], wd[c * 3 + k], acc);
    }
    x[((size_t)b * Ll + l) * 128 + d] = acc;
  }
}

// ---------------------------------------------------------------------------
// gemm_pl — pipelined plain-A 3-split GEMM (R12-proven best, in_proj 47.6 us):
// BM=64 BN=128 BK=64, 256 thr (1Mx4N), A-prefetch across MFMA, B at tile top.
// ---------------------------------------------------------------------------
__global__ __launch_bounds__(256) void gemm_pl(
    const float* __restrict__ A, int lda,
    const u16* __restrict__ Wh, const u16* __restrict__ Wm,
    const u16* __restrict__ Wl,
    float* __restrict__ C, int ldc, int N, int K) {
  __shared__ __align__(16) u16 Lh[64 * 72];
  __shared__ __align__(16) u16 Lm[64 * 72];
  __shared__ __align__(16) u16 Lo[64 * 72];
  const int m0 = blockIdx.x * 64;
  const int n0 = blockIdx.y * 128;
  const int tid = threadIdx.x;
  const int lane = tid & 63;
  const int wn = tid >> 6;
  const int lr = lane & 15;
  const int lq = lane >> 4;

  f32x4 a0[4][2], a1[4][2], a2[4][2];
  const f32x4 zz = {0.f, 0.f, 0.f, 0.f};
#pragma unroll
  for (int i = 0; i < 4; ++i)
#pragma unroll
    for (int j = 0; j < 2; ++j) { a0[i][j] = zz; a1[i][j] = zz; a2[i][j] = zz; }

  const int col0 = n0 + wn * 32 + lr;
  const int col1 = col0 + 16;
  const int c0 = col0 < N ? col0 : N - 1;
  const int c1 = col1 < N ? col1 : N - 1;
  const size_t bo0 = (size_t)c0 * K + lq * 8;
  const size_t bo1 = (size_t)c1 * K + lq * 8;

  const int srow = tid >> 2;
  const int sg = (tid & 3) * 16;
  const int sdst = srow * 72 + sg;
  const int grow = m0 + srow;

  float v[16];
  auto load_a = [&](int kb) {
    const float* pa = A + (size_t)grow * lda + kb + sg;
#pragma unroll
    for (int q = 0; q < 4; ++q) {
      float4 a = *(const float4*)(pa + q * 4);
      v[q * 4 + 0] = a.x; v[q * 4 + 1] = a.y;
      v[q * 4 + 2] = a.z; v[q * 4 + 3] = a.w;
    }
  };

  const int T = K / 64;
  load_a(0);
  for (int t = 0; t < T; ++t) {
    const int kb = t * 64;
    s16x8 bh0[2], bh1[2], bm0[2], bm1[2], bl0[2], bl1[2];
#pragma unroll
    for (int kc = 0; kc < 2; ++kc) {
      const int ko = kb + kc * 32;
      bh0[kc] = *(const s16x8*)(Wh + bo0 + ko);
      bh1[kc] = *(const s16x8*)(Wh + bo1 + ko);
      bm0[kc] = *(const s16x8*)(Wm + bo0 + ko);
      bm1[kc] = *(const s16x8*)(Wm + bo1 + ko);
      bl0[kc] = *(const s16x8*)(Wl + bo0 + ko);
      bl1[kc] = *(const s16x8*)(Wl + bo1 + ko);
    }
    s16x8 h8a, m8a, l8a, h8b, m8b, l8b;
#pragma unroll
    for (int j = 0; j < 8; ++j) {
      u16 h, m, l;
      split3(v[j], h, m, l);
      h8a[j] = (short)h; m8a[j] = (short)m; l8a[j] = (short)l;
    }
#pragma unroll
    for (int j = 0; j < 8; ++j) {
      u16 h, m, l;
      split3(v[8 + j], h, m, l);
      h8b[j] = (short)h; m8b[j] = (short)m; l8b[j] = (short)l;
    }
    *(s16x8*)&Lh[sdst] = h8a; *(s16x8*)&Lh[sdst + 8] = h8b;
    *(s16x8*)&Lm[sdst] = m8a; *(s16x8*)&Lm[sdst + 8] = m8b;
    *(s16x8*)&Lo[sdst] = l8a; *(s16x8*)&Lo[sdst + 8] = l8b;
    __syncthreads();
    if (t + 1 < T) load_a(kb + 64);
#pragma unroll
    for (int kc = 0; kc < 2; ++kc) {
#pragma unroll
      for (int mf = 0; mf < 4; ++mf) {
        const int ar = (mf * 16 + lr) * 72 + kc * 32 + lq * 8;
        const s16x8 ah = *(const s16x8*)&Lh[ar];
        const s16x8 am = *(const s16x8*)&Lm[ar];
        const s16x8 al = *(const s16x8*)&Lo[ar];
        a0[mf][0] = mfma_bf(ah, bh0[kc], a0[mf][0]);
        a0[mf][1] = mfma_bf(ah, bh1[kc], a0[mf][1]);
        a1[mf][0] = mfma_bf(ah, bm0[kc], a1[mf][0]);
        a1[mf][1] = mfma_bf(ah, bm1[kc], a1[mf][1]);
        a1[mf][0] = mfma_bf(am, bh0[kc], a1[mf][0]);
        a1[mf][1] = mfma_bf(am, bh1[kc], a1[mf][1]);
        a2[mf][0] = mfma_bf(ah, bl0[kc], a2[mf][0]);
        a2[mf][1] = mfma_bf(ah, bl1[kc], a2[mf][1]);
        a2[mf][0] = mfma_bf(al, bh0[kc], a2[mf][0]);
        a2[mf][1] = mfma_bf(al, bh1[kc], a2[mf][1]);
        a2[mf][0] = mfma_bf(am, bm0[kc], a2[mf][0]);
        a2[mf][1] = mfma_bf(am, bm1[kc], a2[mf][1]);
      }
    }
    __syncthreads();
  }
#pragma unroll
  for (int mf = 0; mf < 4; ++mf) {
#pragma unroll
    for (int nf = 0; nf < 2; ++nf) {
      const int col = n0 + wn * 32 + nf * 16 + lr;
      if (col < N) {
#pragma unroll
        for (int r = 0; r < 4; ++r) {
          const int row = m0 + mf * 16 + lq * 4 + r;
          C[(size_t)row * ldc + col] =
              fmaf(C8, fmaf(C8, a2[mf][nf][r], a1[mf][nf][r]), a0[mf][nf][r]);
        }
      }
    }
  }
}

// ---------------------------------------------------------------------------
// gemm_fc — fused conv+silu x_proj GEMM (R8/R12-proven)
// ---------------------------------------------------------------------------
__global__ __launch_bounds__(256) void gemm_fc(
    const float* __restrict__ A,
    const float* __restrict__ cw, const float* __restrict__ cb,
    const u16* __restrict__ Wh, const u16* __restrict__ Wm,
    const u16* __restrict__ Wl,
    float* __restrict__ C, int ldc, int N, int K) {
  __shared__ __align__(16) u16 Lh[64 * 40];
  __shared__ __align__(16) u16 Lm[64 * 40];
  __shared__ __align__(16) u16 Lo[64 * 40];
  const int m0 = blockIdx.x * 64;
  const int n0 = blockIdx.y * 128;
  const int tid = threadIdx.x;
  const int lane = tid & 63;
  const int wn = tid >> 6;
  const int lr = lane & 15;
  const int lq = lane >> 4;

  f32x4 a0[4][2], a1[4][2], a2[4][2];
  const f32x4 zz = {0.f, 0.f, 0.f, 0.f};
#pragma unroll
  for (int i = 0; i < 4; ++i)
#pragma unroll
    for (int j = 0; j < 2; ++j) { a0[i][j] = zz; a1[i][j] = zz; a2[i][j] = zz; }

  const int col0 = n0 + wn * 32 + lr;
  const int col1 = col0 + 16;
  const int c0 = col0 < N ? col0 : N - 1;
  const int c1 = col1 < N ? col1 : N - 1;
  const size_t bo0 = (size_t)c0 * K + lq * 8;
  const size_t bo1 = (size_t)c1 * K + lq * 8;

  const int srow = tid >> 2;          // 0..63
  const int sg = (tid & 3) * 8;       // k-chunk of 8
  const int sdst = srow * 40 + sg;
  const int grow = m0 + srow;

  for (int k0 = 0; k0 < K; k0 += 32) {
    float v[8];
    {
      const int l = grow & (Ll - 1);
      const float* px = A + (size_t)grow * 512 + k0 + sg;
      const float4 z4 = make_float4(0.f, 0.f, 0.f, 0.f);
      float4 r0a = *(const float4*)px;
      float4 r0b = *(const float4*)(px + 4);
      float4 r1a = z4, r1b = z4, r2a = z4, r2b = z4, r3a = z4, r3b = z4;
      if (l >= 1) { r1a = *(const float4*)(px - 512);  r1b = *(const float4*)(px - 508); }
      if (l >= 2) { r2a = *(const float4*)(px - 1024); r2b = *(const float4*)(px - 1020); }
      if (l >= 3) { r3a = *(const float4*)(px - 1536); r3b = *(const float4*)(px - 1532); }
      const float* cwp = cw + (size_t)(k0 + sg) * 4;
      const float4 w0 = *(const float4*)(cwp + 0);
      const float4 w1 = *(const float4*)(cwp + 4);
      const float4 w2 = *(const float4*)(cwp + 8);
      const float4 w3 = *(const float4*)(cwp + 12);
      const float4 w4 = *(const float4*)(cwp + 16);
      const float4 w5 = *(const float4*)(cwp + 20);
      const float4 w6 = *(const float4*)(cwp + 24);
      const float4 w7 = *(const float4*)(cwp + 28);
      const float4 cba = *(const float4*)(cb + k0 + sg);
      const float4 cbb = *(const float4*)(cb + k0 + sg + 4);
      v[0] = conv_u(r3a.x, r2a.x, r1a.x, r0a.x, w0, cba.x);
      v[1] = conv_u(r3a.y, r2a.y, r1a.y, r0a.y, w1, cba.y);
      v[2] = conv_u(r3a.z, r2a.z, r1a.z, r0a.z, w2, cba.z);
      v[3] = conv_u(r3a.w, r2a.w, r1a.w, r0a.w, w3, cba.w);
      v[4] = conv_u(r3b.x, r2b.x, r1b.x, r0b.x, w4, cbb.x);
      v[5] = conv_u(r3b.y, r2b.y, r1b.y, r0b.y, w5, cbb.y);
      v[6] = conv_u(r3b.z, r2b.z, r1b.z, r0b.z, w6, cbb.z);
      v[7] = conv_u(r3b.w, r2b.w, r1b.w, r0b.w, w7, cbb.w);
    }
    s16x8 h8, m8, l8;
#pragma unroll
    for (int j = 0; j < 8; ++j) {
      u16 h, m, l;
      split3(v[j], h, m, l);
      h8[j] = (short)h; m8[j] = (short)m; l8[j] = (short)l;
    }
    *(s16x8*)&Lh[sdst] = h8;
    *(s16x8*)&Lm[sdst] = m8;
    *(s16x8*)&Lo[sdst] = l8;
    __syncthreads();
    const s16x8 bh0 = *(const s16x8*)(Wh + bo0 + k0);
    const s16x8 bh1 = *(const s16x8*)(Wh + bo1 + k0);
    const s16x8 bm0 = *(const s16x8*)(Wm + bo0 + k0);
    const s16x8 bm1 = *(const s16x8*)(Wm + bo1 + k0);
    const s16x8 bl0 = *(const s16x8*)(Wl + bo0 + k0);
    const s16x8 bl1 = *(const s16x8*)(Wl + bo1 + k0);
#pragma unroll
    for (int mf = 0; mf < 4; ++mf) {
      const int ar = (mf * 16 + lr) * 40 + lq * 8;
      const s16x8 ah = *(const s16x8*)&Lh[ar];
      const s16x8 am = *(const s16x8*)&Lm[ar];
      const s16x8 al = *(const s16x8*)&Lo[ar];
      a0[mf][0] = mfma_bf(ah, bh0, a0[mf][0]);
      a1[mf][0] = mfma_bf(ah, bm0, a1[mf][0]);
      a1[mf][0] = mfma_bf(am, bh0, a1[mf][0]);
      a2[mf][0] = mfma_bf(ah, bl0, a2[mf][0]);
      a2[mf][0] = mfma_bf(al, bh0, a2[mf][0]);
      a2[mf][0] = mfma_bf(am, bm0, a2[mf][0]);
      a0[mf][1] = mfma_bf(ah, bh1, a0[mf][1]);
      a1[mf][1] = mfma_bf(ah, bm1, a1[mf][1]);
      a1[mf][1] = mfma_bf(am, bh1, a1[mf][1]);
      a2[mf][1] = mfma_bf(ah, bl1, a2[mf][1]);
      a2[mf][1] = mfma_bf(al, bh1, a2[mf][1]);
      a2[mf][1] = mfma_bf(am, bm1, a2[mf][1]);
    }
    __syncthreads();
  }
#pragma unroll
  for (int mf = 0; mf < 4; ++mf) {
#pragma unroll
    for (int nf = 0; nf < 2; ++nf) {
      const int col = n0 + wn * 32 + nf * 16 + lr;
      if (col < N) {
#pragma unroll
        for (int r = 0; r < 4; ++r) {
          const int row = m0 + mf * 16 + lq * 4 + r;
          C[(size_t)row * ldc + col] =
              fmaf(C8, fmaf(C8, a2[mf][nf][r], a1[mf][nf][r]), a0[mf][nf][r]);
        }
      }
    }
  }
}

// ---------------------------------------------------------------------------
// Selective scan (R12-proven; u on-the-fly via rolling 4-window)
// ---------------------------------------------------------------------------
#define LOAD_A2(base)                                                        \
  float4 a2a = *(const float4*)((base));                                     \
  float4 a2b = *(const float4*)((base) + 4);                                 \
  float4 a2c = *(const float4*)((base) + 8);                                 \
  float4 a2d = *(const float4*)((base) + 12);                                \
  a2a.x = -expf(a2a.x) * LOG2E; a2a.y = -expf(a2a.y) * LOG2E;                \
  a2a.z = -expf(a2a.z) * LOG2E; a2a.w = -expf(a2a.w) * LOG2E;                \
  a2b.x = -expf(a2b.x) * LOG2E; a2b.y = -expf(a2b.y) * LOG2E;                \
  a2b.z = -expf(a2b.z) * LOG2E; a2b.w = -expf(a2b.w) * LOG2E;                \
  a2c.x = -expf(a2c.x) * LOG2E; a2c.y = -expf(a2c.y) * LOG2E;                \
  a2c.z = -expf(a2c.z) * LOG2E; a2c.w = -expf(a2c.w) * LOG2E;                \
  a2d.x = -expf(a2d.x) * LOG2E; a2d.y = -expf(a2d.y) * LOG2E;                \
  a2d.z = -expf(a2d.z) * LOG2E; a2d.w = -expf(a2d.w) * LOG2E;

#define DT_FROM_Q(q0, q1, w0, w1, dtbv)                                      \
  float dtr = (dtbv);                                                        \
  dtr = fmaf((q0).x, (w0).x, dtr); dtr = fmaf((q0).y, (w0).y, dtr);          \
  dtr = fmaf((q0).z, (w0).z, dtr); dtr = fmaf((q0).w, (w0).w, dtr);          \
  dtr = fmaf((q1).x, (w1).x, dtr); dtr = fmaf((q1).y, (w1).y, dtr);          \
  dtr = fmaf((q1).z, (w1).z, dtr); dtr = fmaf((q1).w, (w1).w, dtr);

#define UPD1(H, A, Bv)                                                       \
  (H).x = fmaf(hexp2(sp * (A).x), (H).x, dtu * (Bv).x);                      \
  (H).y = fmaf(hexp2(sp * (A).y), (H).y, dtu * (Bv).y);                      \
  (H).z = fmaf(hexp2(sp * (A).z), (H).z, dtu * (Bv).z);                      \
  (H).w = fmaf(hexp2(sp * (A).w), (H).w, dtu * (Bv).w);

#define UPD3(H, A, Bv, Cv)                                                   \
  (H).x = fmaf(hexp2(sp * (A).x), (H).x, dtu * (Bv).x);                      \
  y = fmaf((H).x, (Cv).x, y);                                                \
  (H).y = fmaf(hexp2(sp * (A).y), (H).y, dtu * (Bv).y);                      \
  y = fmaf((H).y, (Cv).y, y);                                                \
  (H).z = fmaf(hexp2(sp * (A).z), (H).z, dtu * (Bv).z);                      \
  y = fmaf((H).z, (Cv).z, y);                                                \
  (H).w = fmaf(hexp2(sp * (A).w), (H).w, dtu * (Bv).w);                      \
  y = fmaf((H).w, (Cv).w, y);

__global__ __launch_bounds__(256) void k_scan_ph1(
    const float* __restrict__ xz, const float* __restrict__ dbl,
    const float* __restrict__ cw, const float* __restrict__ cb,
    const float* __restrict__ dtw, const float* __restrict__ dtb,
    const float* __restrict__ alog, float* __restrict__ hloc,
    float* __restrict__ sdtc) {
  const int b = blockIdx.x / NC;
  const int c = blockIdx.x % NC;
  const int d = threadIdx.x;
  LOAD_A2(alog + d * 16)
  const float4 w0 = *(const float4*)(dtw + d * 8);
  const float4 w1 = *(const float4*)(dtw + d * 8 + 4);
  const float dtbv = dtb[d];
  const float4 cwd = *(const float4*)(cw + d * 4);
  const float cbd = cb[d];
  float4 ha = make_float4(0.f, 0.f, 0.f, 0.f);
  float4 hb = ha, hc = ha, hd = ha;
  float sdt = 0.f;
  const float* xb = xz + (size_t)b * Ll * 512 + d;
  const float* db = dbl + (size_t)b * Ll * 40;
  const int l0 = c * CL;
  float x3 = l0 >= 3 ? xb[(size_t)(l0 - 3) * 512] : 0.f;
  float x2 = l0 >= 2 ? xb[(size_t)(l0 - 2) * 512] : 0.f;
  float x1 = l0 >= 1 ? xb[(size_t)(l0 - 1) * 512] : 0.f;
  for (int l = l0; l < l0 + CL; ++l) {
    const float x0 = xb[(size_t)l * 512];
    const float uv = conv_u(x3, x2, x1, x0, cwd, cbd);
    x3 = x2; x2 = x1; x1 = x0;
    const float* dr = db + (size_t)l * 40;
    const float4 q0 = *(const float4*)(dr);
    const float4 q1 = *(const float4*)(dr + 4);
    const float4 bfa = *(const float4*)(dr + 8);
    const float4 bfb = *(const float4*)(dr + 12);
    const float4 bfc = *(const float4*)(dr + 16);
    const float4 bfd = *(const float4*)(dr + 20);
    DT_FROM_Q(q0, q1, w0, w1, dtbv)
    const float sp = softplus_f(dtr);
    sdt += sp;
    const float dtu = sp * uv;
    UPD1(ha, a2a, bfa)
    UPD1(hb, a2b, bfb)
    UPD1(hc, a2c, bfc)
    UPD1(hd, a2d, bfd)
  }
  const size_t o = (size_t)(b * NC + c) * 256 + d;
  *(float4*)(hloc + o * 16 + 0)  = ha;
  *(float4*)(hloc + o * 16 + 4)  = hb;
  *(float4*)(hloc + o * 16 + 8)  = hc;
  *(float4*)(hloc + o * 16 + 12) = hd;
  sdtc[o] = sdt;
}

// Cross-chunk combine IN PLACE: hloc[c] local-end-state -> exact start-state.
__global__ __launch_bounds__(256) void k_scan_ph2(
    const float* __restrict__ alog, float* __restrict__ hloc,
    const float* __restrict__ sdtc) {
  const int b = blockIdx.x >> 4;
  const int dg = blockIdx.x & 15;
  const int d = dg * 16 + (threadIdx.x >> 4);
  const int s = threadIdx.x & 15;
  const float A2 = -expf(alog[d * 16 + s]) * LOG2E;
  float hs = 0.f;
  for (int c = 0; c < NC; ++c) {
    const size_t o = (size_t)(b * NC + c) * 256 + d;
    const float tmp = hloc[o * 16 + s];
    hloc[o * 16 + s] = hs;
    hs = fmaf(hexp2(A2 * sdtc[o]), hs, tmp);
  }
}

// Re-scan from exact h_start; y = (scan_y + u*D)*silu(z) -> ybuf (B,L,256)
__global__ __launch_bounds__(256) void k_scan_ph3(
    const float* __restrict__ xz, const float* __restrict__ dbl,
    const float* __restrict__ cw, const float* __restrict__ cb,
    const float* __restrict__ dtw, const float* __restrict__ dtb,
    const float* __restrict__ alog, const float* __restrict__ Dv,
    const float* __restrict__ hstart, float* __restrict__ ybuf) {
  const int b = blockIdx.x / NC;
  const int c = blockIdx.x % NC;
  const int d = threadIdx.x;
  LOAD_A2(alog + d * 16)
  const float4 w0 = *(const float4*)(dtw + d * 8);
  const float4 w1 = *(const float4*)(dtw + d * 8 + 4);
  const float dtbv = dtb[d];
  const float Dd = Dv[d];
  const float4 cwd = *(const float4*)(cw + d * 4);
  const float cbd = cb[d];
  const size_t o = (size_t)(b * NC + c) * 256 + d;
  float4 ha = *(const float4*)(hstart + o * 16 + 0);
  float4 hb = *(const float4*)(hstart + o * 16 + 4);
  float4 hc = *(const float4*)(hstart + o * 16 + 8);
  float4 hd = *(const float4*)(hstart + o * 16 + 12);
  const float* xb = xz + (size_t)b * Ll * 512 + d;
  const float* db = dbl + (size_t)b * Ll * 40;
  float* yb = ybuf + (size_t)b * Ll * 256 + d;
  const int l0 = c * CL;
  float x3 = l0 >= 3 ? xb[(size_t)(l0 - 3) * 512] : 0.f;
  float x2 = l0 >= 2 ? xb[(size_t)(l0 - 2) * 512] : 0.f;
  float x1 = l0 >= 1 ? xb[(size_t)(l0 - 1) * 512] : 0.f;
  for (int l = l0; l < l0 + CL; ++l) {
    const float x0 = xb[(size_t)l * 512];
    const float uv = conv_u(x3, x2, x1, x0, cwd, cbd);
    x3 = x2; x2 = x1; x1 = x0;
    const float* dr = db + (size_t)l * 40;
    const float4 q0 = *(const float4*)(dr);
    const float4 q1 = *(const float4*)(dr + 4);
    const float4 bfa = *(const float4*)(dr + 8);
    const float4 bfb = *(const float4*)(dr + 12);
    const float4 bfc = *(const float4*)(dr + 16);
    const float4 bfd = *(const float4*)(dr + 20);
    const float4 cfa = *(const float4*)(dr + 24);
    const float4 cfb = *(const float4*)(dr + 28);
    const float4 cfc = *(const float4*)(dr + 32);
    const float4 cfd = *(const float4*)(dr + 36);
    DT_FROM_Q(q0, q1, w0, w1, dtbv)
    const float sp = softplus_f(dtr);
    const float dtu = sp * uv;
    float y = 0.f;
    UPD3(ha, a2a, bfa, cfa)
    UPD3(hb, a2b, bfb, cfb)
    UPD3(hc, a2c, bfc, cfc)
    UPD3(hd, a2d, bfd, cfd)
    y = fmaf(uv, Dd, y);
    const float zv = xb[(size_t)l * 512 + 256];
    yb[(size_t)l * 256] = y * (zv * sigmoid_f(zv));
  }
}

// ---------------------------------------------------------------------------
// Pooling, two-stage
// ---------------------------------------------------------------------------
__global__ __launch_bounds__(128) void k_pool_part(const float* __restrict__ x,
                                                   float* __restrict__ part) {
  const int b = blockIdx.x >> 5;
  const int c = blockIdx.x & 31;
  const int m = threadIdx.x;
  const float* xb = x + (size_t)b * Ll * 128 + (size_t)c * 128 * 128 + m;
  float s = 0.f;
#pragma unroll 4
  for (int l = 0; l < 128; ++l) s += xb[(size_t)l * 128];
  part[(size_t)blockIdx.x * 128 + m] = s;
}

__global__ __launch_bounds__(128) void k_pool_fin(const float* __restrict__ part,
                                                  float* __restrict__ out) {
  const int b = blockIdx.x, m = threadIdx.x;
  float p = 0.f;
#pragma unroll
  for (int c = 0; c < 32; ++c) p += part[((size_t)b * 32 + c) * 128 + m];
  p *= (1.f / Ll);
  __shared__ float pm[128];
  __shared__ float sq[128];
  pm[m] = p;
  sq[m] = p * p;
  __syncthreads();
  for (int wd = 64; wd >= 1; wd >>= 1) {
    if (m < wd) sq[m] += sq[m + wd];
    __syncthreads();
  }
  out[b * 128 + m] = pm[m] / fmaxf(sqrtf(sq[0]), 1e-12f);
}

// ---------------------------------------------------------------------------
extern "C" void kernel_launch(void* const* d_in, const int* in_sizes, int n_in,
                              void* d_out, int out_size, void* d_ws, size_t ws_size,
                              hipStream_t stream) {
  (void)in_sizes; (void)n_in; (void)out_size; (void)ws_size;
  const float* t    = (const float*)d_in[0];
  const float* embw = (const float*)d_in[1];
  const float* inw  = (const float*)d_in[2];
  const float* cw   = (const float*)d_in[3];
  const float* cb   = (const float*)d_in[4];
  const float* xpw  = (const float*)d_in[5];
  const float* dtw  = (const float*)d_in[6];
  const float* dtb  = (const float*)d_in[7];
  const float* alog = (const float*)d_in[8];
  const float* Dv   = (const float*)d_in[9];
  const float* ow   = (const float*)d_in[10];

  float* wsf  = (float*)d_ws;
  float* xz   = wsf;                   // (B,L,512)      16777216 f
  float* xb   = xz + 16777216;         // (B,L,128)       4194304 f
  float* ybuf = xb + 4194304;          // (B,L,256)       8388608 f
  float* dblb = ybuf + 8388608;        // (B,L,40)        1310720 f
  float* hloc = dblb + 1310720;        // (B,NC,256,16)   4194304 f
  float* sdtc = hloc + 4194304;        // (B,NC,256)       262144 f
  float* pool = sdtc + 262144;         // (B,32,128)        32768 f
  float* wtb  = pool + 32768;          // bf16 weight planes
  u16* wih = (u16*)(wtb);
  u16* wim = (u16*)(wtb + 65536);
  u16* wil = (u16*)(wtb + 131072);
  u16* wxh = (u16*)(wtb + 196608);
  u16* wxm = (u16*)(wtb + 206848);
  u16* wxl = (u16*)(wtb + 217088);
  u16* woh = (u16*)(wtb + 227328);
  u16* wom = (u16*)(wtb + 260096);
  u16* wol = (u16*)(wtb + 292864);
  float* outp = (float*)d_out;

  k_split3<<<dim3(512), 256, 0, stream>>>(inw, wih, wim, wil, 131072);
  k_split3<<<dim3(80),  256, 0, stream>>>(xpw, wxh, wxm, wxl, 20480);
  k_split3<<<dim3(256), 256, 0, stream>>>(ow,  woh, wom, wol, 65536);

  k_embed<<<dim3(Bb * (Ll / 32)), dim3(128), 0, stream>>>(t, embw, xb);

  for (int layer = 0; layer < 2; ++layer) {
    const u16* wih_l = wih + (size_t)layer * 512 * 128;
    const u16* wim_l = wim + (size_t)layer * 512 * 128;
    const u16* wil_l = wil + (size_t)layer * 512 * 128;
    const u16* wxh_l = wxh + (size_t)layer * 40 * 256;
    const u16* wxm_l = wxm + (size_t)layer * 40 * 256;
    const u16* wxl_l = wxl + (size_t)layer * 40 * 256;
    const u16* woh_l = woh + (size_t)layer * 128 * 256;
    const u16* wom_l = wom + (size_t)layer * 128 * 256;
    const u16* wol_l = wol + (size_t)layer * 128 * 256;
    const float* cw_l  = cw + layer * 256 * 4;
    const float* cb_l  = cb + layer * 256;
    const float* dtw_l = dtw + layer * 256 * 8;
    const float* dtb_l = dtb + layer * 256;
    const float* al_l  = alog + layer * 256 * 16;
    const float* D_l   = Dv + layer * 256;

    // in_proj: (M=32768, N=512, K=128) -> xz fp32  [pipelined path]
    gemm_pl<<<dim3(Mrows / 64, 4), 256, 0, stream>>>(
        xb, 128, wih_l, wim_l, wil_l, xz, 512, 512, 128);
    // x_proj fused conv+silu: (N=40, K=256) -> dbl fp32  [R8 FUSE path]
    gemm_fc<<<dim3(Mrows / 64, 1), 256, 0, stream>>>(
        xz, cw_l, cb_l, wxh_l, wxm_l, wxl_l, dblb, 40, 40, 256);
    // chunked selective scan (u on-the-fly from xz)
    k_scan_ph1<<<dim3(Bb * NC), 256, 0, stream>>>(xz, dblb, cw_l, cb_l,
                                                  dtw_l, dtb_l, al_l, hloc, sdtc);
    k_scan_ph2<<<dim3(Bb * 16), 256, 0, stream>>>(al_l, hloc, sdtc);
    k_scan_ph3<<<dim3(Bb * NC), 256, 0, stream>>>(xz, dblb, cw_l, cb_l,
                                                  dtw_l, dtb_l, al_l, D_l,
                                                  hloc, ybuf);
    // out_proj: (N=128, K=256) A = ybuf -> xb fp32  [pipelined path]
    gemm_pl<<<dim3(Mrows / 64, 1), 256, 0, stream>>>(
        ybuf, 256, woh_l, wom_l, wol_l, xb, 128, 128, 256);
  }

  k_pool_part<<<dim3(Bb * 32), 128, 0, stream>>>(xb, pool);
  k_pool_fin<<<dim3(Bb), 128, 0, stream>>>(pool, outp);
}